// Round 6
// baseline (109.029 us; speedup 1.0000x reference)
//
#include <hip/hip_runtime.h>

#define NH 8
#define NF 16
#define NNODE 1024
#define INF_F 200
#define OUTF 128
#define IT 16           // i-nodes per block (traffic: 64 i-tiles x ~1MB)
#define JS 8            // j-slices (parallelism: 64*8 = 512 blocks)
#define JCH 64          // j-chunk = one wave width
#define NCH (NNODE / JS / JCH)   // 2 chunks per block
#define ESTR (JCH + 2)  // e_lds row stride 66: PV reads hit 16 distinct banks
#define NEG_INF (-__builtin_huge_valf())

// ---------------- Kernel 1: g_l = x @ W_l, g_r = x @ W_r (all f32) ----------
// (validated in round 3: passed with absmax 2.44e-4)
__global__ __launch_bounds__(256) void proj_kernel(
        const float* __restrict__ x,
        const float* __restrict__ Wl,
        const float* __restrict__ Wr,
        float* __restrict__ gl,
        float* __restrict__ gr) {
    __shared__ float xs[8 * INF_F];
    const float* __restrict__ W = blockIdx.y ? Wr : Wl;
    float* __restrict__ g = blockIdx.y ? gr : gl;
    const int i0 = blockIdx.x * 8;
    const int tid = threadIdx.x;

    {
        const float4* src = (const float4*)(x + i0 * INF_F);
        float4* dst = (float4*)xs;
        for (int t = tid; t < (8 * INF_F) / 4; t += 256) dst[t] = src[t];
    }
    __syncthreads();

    const int c = tid & 127;
    const int r0 = (tid >> 7) * 4;
    float acc[4] = {0.f, 0.f, 0.f, 0.f};
#pragma unroll 4
    for (int k = 0; k < INF_F; ++k) {
        const float w = W[k * OUTF + c];
#pragma unroll
        for (int r = 0; r < 4; ++r)
            acc[r] = fmaf(xs[(r0 + r) * INF_F + k], w, acc[r]);
    }
#pragma unroll
    for (int r = 0; r < 4; ++r)
        g[(i0 + r0 + r) * OUTF + c] = acc[r];
}

// ---------------- Kernel 2: flash-style partial GAT (register state) --------
// Block = (i-tile of 16 nodes) x (j-slice of 128 cols). 8 waves = 8 heads.
// Per chunk: score phase (lane = j) writes RAW e to e_lds; barrier; PV phase
// (lane = (iq, fq)) keeps online (m, s, acc) entirely in registers.
// No exec-masked LDS writes, no cross-chunk LDS state.
__global__ __launch_bounds__(512) void gat_partial(
        const float* __restrict__ gl,
        const float* __restrict__ gr,
        const int* __restrict__ adj,
        const float* __restrict__ attn_w,
        float* __restrict__ outp,   // [JS][NNODE][OUTF]
        float* __restrict__ pm,     // [JS][NNODE][NH]
        float* __restrict__ ps) {   // [JS][NNODE][NH]
    __shared__ float gri[IT][OUTF];           // 8 KB: g_r rows of the i-tile
    __shared__ float e_lds[NH][IT][ESTR];     // 33 KB: raw scores per head

    const int bid = blockIdx.x;
    const int itile = bid >> 3;
    const int js = bid & 7;
    const int i0 = itile * IT;
    const int tid = threadIdx.x;
    const int h = tid >> 6;          // wave = head
    const int lane = tid & 63;

    // stage g_r[i-tile]: 512 threads x float4 = 16 rows x 128 cols, coalesced
    *(float4*)((float*)gri + tid * 4) = *(const float4*)(gr + i0 * OUTF + tid * 4);
    __syncthreads();

    float w[NF];
#pragma unroll
    for (int f = 0; f < NF; ++f) w[f] = attn_w[f];

    const int iq = lane >> 2;        // PV: node within tile
    const int fq = lane & 3;         // PV: f-quad
    float4 acc = {0.f, 0.f, 0.f, 0.f};
    float s_reg = 0.f;
    float m_reg = NEG_INF;

    for (int c = 0; c < NCH; ++c) {
        const int jbase = js * (NNODE / JS) + c * JCH;

        // ---- score phase: lane = j. gl stripe -> regs, reused for all 16 i.
        {
            const int row = jbase + lane;
            float glr[NF];
            {
                const float4* gp = (const float4*)(gl + row * OUTF + h * NF);
                float4 g0 = gp[0], g1 = gp[1], g2 = gp[2], g3 = gp[3];
                glr[0]=g0.x; glr[1]=g0.y; glr[2]=g0.z; glr[3]=g0.w;
                glr[4]=g1.x; glr[5]=g1.y; glr[6]=g1.z; glr[7]=g1.w;
                glr[8]=g2.x; glr[9]=g2.y; glr[10]=g2.z; glr[11]=g2.w;
                glr[12]=g3.x; glr[13]=g3.y; glr[14]=g3.z; glr[15]=g3.w;
            }
#pragma unroll
            for (int i = 0; i < IT; ++i) {
                const float4* ap = (const float4*)(&gri[i][h * NF]);  // broadcast
                float4 a0 = ap[0], a1 = ap[1], a2 = ap[2], a3 = ap[3];
                float ga[NF] = {a0.x,a0.y,a0.z,a0.w, a1.x,a1.y,a1.z,a1.w,
                                a2.x,a2.y,a2.z,a2.w, a3.x,a3.y,a3.z,a3.w};
                float ei = 0.f;
#pragma unroll
                for (int f = 0; f < NF; ++f) {
                    float v = ga[f] + glr[f];
                    v = fmaxf(v, 0.2f * v);          // leaky relu, slope < 1
                    ei = fmaf(v, w[f], ei);
                }
                const int msk = adj[(i0 + i) * NNODE + row];   // coalesced
                e_lds[h][i][lane] = msk ? ei : NEG_INF;
            }
        }
        __syncthreads();   // e_lds writes -> PV reads

        // ---- PV phase: lane = (iq, fq); online (m, s, acc) in registers.
        {
            const float* er = &e_lds[h][iq][0];
            // chunk max: 4-way split scan (breaks the dependent fmax chain)
            float m0 = NEG_INF, m1 = NEG_INF, m2 = NEG_INF, m3 = NEG_INF;
#pragma unroll
            for (int j = 0; j < JCH; j += 4) {
                m0 = fmaxf(m0, er[j]);
                m1 = fmaxf(m1, er[j + 1]);
                m2 = fmaxf(m2, er[j + 2]);
                m3 = fmaxf(m3, er[j + 3]);
            }
            const float m_c = fmaxf(fmaxf(m0, m1), fmaxf(m2, m3));
            const float m_new = fmaxf(m_reg, m_c);
            float mb, scale;
            if (m_new == NEG_INF) { mb = 0.f; scale = 0.f; }  // fully-masked so far
            else { mb = m_new; scale = __expf(m_reg - m_new); } // m_reg=-inf -> 0
            acc.x *= scale; acc.y *= scale; acc.z *= scale; acc.w *= scale;
            s_reg *= scale;
#pragma unroll 8
            for (int j = 0; j < JCH; ++j) {
                const float p = __expf(er[j] - mb);   // e=-inf -> exp(-inf)=0
                const float4 g = *(const float4*)(gr + (jbase + j) * OUTF + h * NF + fq * 4);
                acc.x = fmaf(p, g.x, acc.x);
                acc.y = fmaf(p, g.y, acc.y);
                acc.z = fmaf(p, g.z, acc.z);
                acc.w = fmaf(p, g.w, acc.w);
                s_reg += p;
            }
            m_reg = m_new;
        }
        __syncthreads();   // PV reads done before next chunk overwrites e_lds
    }

    // ---- write slice partials
    {
        const int gi = i0 + iq;
        *(float4*)(outp + js * NNODE * OUTF + gi * OUTF + h * NF + fq * 4) = acc;
        if (fq == 0) {
            pm[js * NNODE * NH + gi * NH + h] = m_reg;
            ps[js * NNODE * NH + gi * NH + h] = s_reg;
        }
    }
}

// ---------------- Kernel 3: merge the JS slice partials ---------------------
__global__ __launch_bounds__(256) void gat_reduce(
        const float* __restrict__ outp,
        const float* __restrict__ pm,
        const float* __restrict__ ps,
        float* __restrict__ out) {
    const int t = blockIdx.x * 256 + threadIdx.x;   // (i, c)
    const int i = t >> 7;
    const int c = t & 127;
    const int h = c >> 4;
    float m[JS];
    float M = NEG_INF;
#pragma unroll
    for (int s = 0; s < JS; ++s) {
        m[s] = pm[s * NNODE * NH + i * NH + h];
        M = fmaxf(M, m[s]);
    }
    float num = 0.f, den = 0.f;
#pragma unroll
    for (int s = 0; s < JS; ++s) {
        const float sc = (m[s] == NEG_INF) ? 0.f : __expf(m[s] - M);  // M finite (self-loop)
        num = fmaf(outp[s * NNODE * OUTF + i * OUTF + c], sc, num);
        den = fmaf(ps[s * NNODE * NH + i * NH + h], sc, den);
    }
    out[t] = num / den;
}

extern "C" void kernel_launch(void* const* d_in, const int* in_sizes, int n_in,
                              void* d_out, int out_size, void* d_ws, size_t ws_size,
                              hipStream_t stream) {
    const float* h   = (const float*)d_in[0];   // [1,1024,200] f32
    const int*   adj = (const int*)d_in[1];     // [1,1024,1024] int32
    const float* Wl  = (const float*)d_in[2];   // [200,128] f32
    const float* Wr  = (const float*)d_in[3];   // [200,128] f32
    const float* aw  = (const float*)d_in[4];   // [16] f32
    float* out = (float*)d_out;                 // [1,1024,128] f32

    float* gl   = (float*)d_ws;                          // 1024*128
    float* gr   = gl + NNODE * OUTF;                     // 1024*128
    float* outp = gr + NNODE * OUTF;                     // JS*1024*128
    float* pm   = outp + JS * NNODE * OUTF;              // JS*1024*8
    float* ps   = pm + JS * NNODE * NH;                  // JS*1024*8

    proj_kernel<<<dim3(128, 2), 256, 0, stream>>>(h, Wl, Wr, gl, gr);
    gat_partial<<<dim3(64 * JS), 512, 0, stream>>>(gl, gr, adj, aw, outp, pm, ps);
    gat_reduce<<<dim3(NNODE * OUTF / 256), 256, 0, stream>>>(outp, pm, ps, out);
}